// Round 1
// baseline (408.116 us; speedup 1.0000x reference)
//
#include <hip/hip_runtime.h>

#define BB 16
#define NN 2048
#define FF 128
#define NEG 0.01f

// ---------------------------------------------------------------------------
// K1: Wh = h @ W  (fp32, LDS-tiled), fused f1 = Wh·a1, f2 = Wh·a2
// block 256 = 32 f-groups(x4 f) * 8 row-slots(x4 rows); 32 rows per block
// ---------------------------------------------------------------------------
__global__ __launch_bounds__(256) void k_wh(const float* __restrict__ h,
                                            const float* __restrict__ Wg,
                                            const float* __restrict__ a,
                                            float* __restrict__ Wh,
                                            float* __restrict__ f1,
                                            float* __restrict__ f2) {
    __shared__ float Ws[64 * 128];   // [k][f] half-K tile (32 KB)
    __shared__ float hsT[64 * 36];   // [k][row] transposed h tile, pad 36 (9 KB)

    const int tid  = threadIdx.x;
    const int fg   = tid & 31;        // f-group
    const int slot = tid >> 5;        // row-slot 0..7
    const int f4   = fg * 4;
    const int rowBase = blockIdx.x * 32;

    float acc[4][4];
#pragma unroll
    for (int r = 0; r < 4; ++r)
#pragma unroll
        for (int c = 0; c < 4; ++c) acc[r][c] = 0.f;

    const float4* Wg4 = (const float4*)Wg;
    const float4* hg4 = (const float4*)h;

    for (int kh = 0; kh < 128; kh += 64) {
        __syncthreads();
        // load W half-tile: 64 x 128 floats = 2048 float4
        for (int idx = tid; idx < 64 * 32; idx += 256) {
            int kk = idx >> 5, ff = idx & 31;
            ((float4*)Ws)[kk * 32 + ff] = Wg4[(size_t)(kh + kk) * 32 + ff];
        }
        // load h tile transposed: 32 rows x 64 k
#pragma unroll
        for (int pass = 0; pass < 2; ++pass) {
            int idx = pass * 256 + tid;            // 0..511
            int kq = idx & 15, row = idx >> 4;     // kq 0..15, row 0..31
            float4 h4 = hg4[(size_t)(rowBase + row) * 32 + (kh >> 2) + kq];
            hsT[(kq * 4 + 0) * 36 + row] = h4.x;
            hsT[(kq * 4 + 1) * 36 + row] = h4.y;
            hsT[(kq * 4 + 2) * 36 + row] = h4.z;
            hsT[(kq * 4 + 3) * 36 + row] = h4.w;
        }
        __syncthreads();
#pragma unroll 8
        for (int kk = 0; kk < 64; ++kk) {
            float4 wv = *(const float4*)&Ws[kk * 128 + f4];
            float4 hv = *(const float4*)&hsT[kk * 36 + slot * 4];
            acc[0][0] += hv.x * wv.x; acc[0][1] += hv.x * wv.y; acc[0][2] += hv.x * wv.z; acc[0][3] += hv.x * wv.w;
            acc[1][0] += hv.y * wv.x; acc[1][1] += hv.y * wv.y; acc[1][2] += hv.y * wv.z; acc[1][3] += hv.y * wv.w;
            acc[2][0] += hv.z * wv.x; acc[2][1] += hv.z * wv.y; acc[2][2] += hv.z * wv.z; acc[2][3] += hv.z * wv.w;
            acc[3][0] += hv.w * wv.x; acc[3][1] += hv.w * wv.y; acc[3][2] += hv.w * wv.z; acc[3][3] += hv.w * wv.w;
        }
    }

    const float4* ag4 = (const float4*)a;
    float4 a1v = ag4[fg];        // a[f4..f4+3]
    float4 a2v = ag4[32 + fg];   // a[128+f4..]

#pragma unroll
    for (int r = 0; r < 4; ++r) {
        int row = rowBase + slot * 4 + r;
        float4 o; o.x = acc[r][0]; o.y = acc[r][1]; o.z = acc[r][2]; o.w = acc[r][3];
        *(float4*)&Wh[(size_t)row * 128 + f4] = o;
        float p1 = acc[r][0] * a1v.x + acc[r][1] * a1v.y + acc[r][2] * a1v.z + acc[r][3] * a1v.w;
        float p2 = acc[r][0] * a2v.x + acc[r][1] * a2v.y + acc[r][2] * a2v.z + acc[r][3] * a2v.w;
#pragma unroll
        for (int m = 16; m >= 1; m >>= 1) {
            p1 += __shfl_xor(p1, m);
            p2 += __shfl_xor(p2, m);
        }
        if (fg == 0) { f1[row] = p1; f2[row] = p2; }
    }
}

// ---------------------------------------------------------------------------
// K2: per batch — sort f1 (scalar exp scans -> softmax denominators D_j ->
// u_j, w_j in f2-sorted order), sort f2 (perm), per-row cut indices KIDX.
// One block of 1024 threads per batch.
// ---------------------------------------------------------------------------
__global__ __launch_bounds__(1024) void k_sort(const float* __restrict__ f1,
                                               const float* __restrict__ f2,
                                               float* __restrict__ Uarr,
                                               float* __restrict__ Warr,
                                               int* __restrict__ PERM,
                                               int* __restrict__ KIDX) {
    __shared__ float sKey[NN];
    __shared__ int   sIdx[NN];
    __shared__ float sSF1[NN];
    __shared__ float bufA[NN];
    __shared__ float bufB[NN];
    __shared__ float sPA[NN + 1];
    __shared__ float sSA[NN + 1];

    const int tid = threadIdx.x;
    const int b   = blockIdx.x;
    const float* f1b = f1 + b * NN;
    const float* f2b = f2 + b * NN;

    // ---- phase 1: sort f1 values ascending ----
    for (int i = tid; i < NN; i += 1024) sKey[i] = f1b[i];
    __syncthreads();
    for (int k = 2; k <= NN; k <<= 1) {
        for (int j = k >> 1; j > 0; j >>= 1) {
            int mask = j - 1;
            int i = ((tid & ~mask) << 1) | (tid & mask);
            int ixj = i | j;
            bool up = ((i & k) == 0);
            float av = sKey[i], bv = sKey[ixj];
            if ((av > bv) == up) { sKey[i] = bv; sKey[ixj] = av; }
            __syncthreads();
        }
    }
    for (int i = tid; i < NN; i += 1024) sSF1[i] = sKey[i];
    __syncthreads();

    // ---- prefix scan of exp(0.01*sf1) -> sPA (exclusive, length N+1) ----
    for (int i = tid; i < NN; i += 1024) bufA[i] = expf(NEG * sSF1[i]);
    {
        float* s = bufA; float* d = bufB;
        for (int dd = 1; dd < NN; dd <<= 1) {
            __syncthreads();
            for (int i = tid; i < NN; i += 1024) {
                float v = s[i];
                if (i >= dd) v += s[i - dd];
                d[i] = v;
            }
            float* t = s; s = d; d = t;
        }
        __syncthreads();
        for (int i = tid; i < NN; i += 1024) sPA[i + 1] = s[i];
        if (tid == 0) sPA[0] = 0.f;
    }
    __syncthreads();

    // ---- suffix scan of exp(sf1) -> sSA (length N+1, sSA[N]=0) ----
    for (int i = tid; i < NN; i += 1024) bufA[i] = expf(sSF1[NN - 1 - i]);
    {
        float* s = bufA; float* d = bufB;
        for (int dd = 1; dd < NN; dd <<= 1) {
            __syncthreads();
            for (int i = tid; i < NN; i += 1024) {
                float v = s[i];
                if (i >= dd) v += s[i - dd];
                d[i] = v;
            }
            float* t = s; s = d; d = t;
        }
        __syncthreads();
        for (int i = tid; i < NN; i += 1024) sSA[NN - 1 - i] = s[i];
        if (tid == 0) sSA[NN] = 0.f;
    }
    __syncthreads();

    // ---- phase 2: sort (f2, idx) pairs ascending ----
    for (int i = tid; i < NN; i += 1024) { sKey[i] = f2b[i]; sIdx[i] = i; }
    __syncthreads();
    for (int k = 2; k <= NN; k <<= 1) {
        for (int j = k >> 1; j > 0; j >>= 1) {
            int mask = j - 1;
            int i = ((tid & ~mask) << 1) | (tid & mask);
            int ixj = i | j;
            bool up = ((i & k) == 0);
            float av = sKey[i], bv = sKey[ixj];
            if ((av > bv) == up) {
                sKey[i] = bv; sKey[ixj] = av;
                int t2 = sIdx[i]; sIdx[i] = sIdx[ixj]; sIdx[ixj] = t2;
            }
            __syncthreads();
        }
    }

    // ---- phase 3: D_j, u_j, w_j in sorted order; PERM ----
    for (int t = tid; t < NN; t += 1024) {
        float f2v = sKey[t];
        float tau = -f2v;
        int lo = 0, hi = NN;
        while (lo < hi) { int m = (lo + hi) >> 1; if (sSF1[m] <= tau) lo = m + 1; else hi = m; }
        float eS = expf(NEG * f2v);   // small-slope factor
        float eF = expf(f2v);         // full factor
        float D = eS * sPA[lo] + eF * sSA[lo];
        float inv = 1.0f / D;
        Uarr[b * NN + t] = eF * inv;
        Warr[b * NN + t] = eS * inv;
        PERM[b * NN + t] = sIdx[t];
    }

    // ---- phase 4: per-row cut index k_i = #{t: sf2[t] <= -f1[i]} ----
    for (int i = tid; i < NN; i += 1024) {
        float tau = -f1b[i];
        int lo = 0, hi = NN;
        while (lo < hi) { int m = (lo + hi) >> 1; if (sKey[m] <= tau) lo = m + 1; else hi = m; }
        KIDX[b * NN + i] = lo;
    }
}

// ---------------------------------------------------------------------------
// K3: chunk totals for the 128-wide vector prefix sums (16 chunks x 128 t)
// ---------------------------------------------------------------------------
__global__ __launch_bounds__(128) void k_chunk(const float* __restrict__ Wh,
                                               const float* __restrict__ Uarr,
                                               const float* __restrict__ Warr,
                                               const int* __restrict__ PERM,
                                               float* __restrict__ CU,
                                               float* __restrict__ CW) {
    int blk = blockIdx.x;               // b*16 + c
    int b = blk >> 4, c = blk & 15;
    int f = threadIdx.x;
    int base = b * NN + c * 128;
    const float* Whb = Wh + (size_t)b * NN * FF;
    float aU = 0.f, aW = 0.f;
#pragma unroll 4
    for (int t = 0; t < 128; ++t) {
        int j = PERM[base + t];
        float uv = Uarr[base + t], wv = Warr[base + t];
        float whv = Whb[(size_t)j * FF + f];
        aU += uv * whv; aW += wv * whv;
    }
    CU[(size_t)blk * 128 + f] = aU;
    CW[(size_t)blk * 128 + f] = aW;
}

// ---------------------------------------------------------------------------
// K4: in-place exclusive scan of the 16 chunk totals per (b,f)
// ---------------------------------------------------------------------------
__global__ __launch_bounds__(128) void k_offsets(float* __restrict__ CU,
                                                 float* __restrict__ CW) {
    int b = blockIdx.x, f = threadIdx.x;
    float aU = 0.f, aW = 0.f;
#pragma unroll
    for (int c = 0; c < 16; ++c) {
        size_t idx = (size_t)(b * 16 + c) * 128 + f;
        float tU = CU[idx], tW = CW[idx];
        CU[idx] = aU; CW[idx] = aW;
        aU += tU; aW += tW;
    }
}

// ---------------------------------------------------------------------------
// K5: write exclusive vector prefix sums PU/PW (rows 0..N; row N = totals)
// ---------------------------------------------------------------------------
__global__ __launch_bounds__(128) void k_prefix(const float* __restrict__ Wh,
                                                const float* __restrict__ Uarr,
                                                const float* __restrict__ Warr,
                                                const int* __restrict__ PERM,
                                                const float* __restrict__ CU,
                                                const float* __restrict__ CW,
                                                float* __restrict__ PU,
                                                float* __restrict__ PW) {
    int blk = blockIdx.x;
    int b = blk >> 4, c = blk & 15;
    int f = threadIdx.x;
    int base = b * NN + c * 128;
    const float* Whb = Wh + (size_t)b * NN * FF;
    float aU = CU[(size_t)blk * 128 + f];
    float aW = CW[(size_t)blk * 128 + f];
    size_t rowB = (size_t)b * (NN + 1);
#pragma unroll 4
    for (int t = 0; t < 128; ++t) {
        int g = c * 128 + t;
        PU[(rowB + g) * FF + f] = aU;
        PW[(rowB + g) * FF + f] = aW;
        int j = PERM[base + t];
        float whv = Whb[(size_t)j * FF + f];
        aU += Uarr[base + t] * whv;
        aW += Warr[base + t] * whv;
    }
    if (c == 15) {
        PU[(rowB + NN) * FF + f] = aU;
        PW[(rowB + NN) * FF + f] = aW;
    }
}

// ---------------------------------------------------------------------------
// K6: combine: out[b,i,f] = e^{0.01 f1i} * PW[k_i] + e^{f1i} * (TotU - PU[k_i])
// ---------------------------------------------------------------------------
__global__ __launch_bounds__(256) void k_out(const float* __restrict__ PU,
                                             const float* __restrict__ PW,
                                             const float* __restrict__ f1,
                                             const int* __restrict__ KIDX,
                                             float* __restrict__ out) {
    int rowId = blockIdx.x * 2 + (threadIdx.x >> 7);
    int f = threadIdx.x & 127;
    int b = rowId >> 11;
    int k = KIDX[rowId];
    float f1v = f1[rowId];
    float alpha = expf(NEG * f1v);
    float beta  = expf(f1v);
    size_t rowB = (size_t)b * (NN + 1);
    float totU = PU[(rowB + NN) * FF + f];
    float pu   = PU[(rowB + k) * FF + f];
    float pw   = PW[(rowB + k) * FF + f];
    out[(size_t)rowId * FF + f] = alpha * pw + beta * (totU - pu);
}

// ---------------------------------------------------------------------------
extern "C" void kernel_launch(void* const* d_in, const int* in_sizes, int n_in,
                              void* d_out, int out_size, void* d_ws, size_t ws_size,
                              hipStream_t stream) {
    const float* h  = (const float*)d_in[0];
    // d_in[1] = adj — unused by the reference; never read.
    const float* W  = (const float*)d_in[2];
    const float* a  = (const float*)d_in[3];
    float* out = (float*)d_out;

    float* ws = (float*)d_ws;
    float* Wh   = ws;  ws += (size_t)BB * NN * FF;         // 4,194,304
    float* f1   = ws;  ws += BB * NN;                      // 32,768
    float* f2   = ws;  ws += BB * NN;
    float* Uarr = ws;  ws += BB * NN;
    float* Warr = ws;  ws += BB * NN;
    float* CU   = ws;  ws += BB * 16 * FF;                 // 32,768
    float* CW   = ws;  ws += BB * 16 * FF;
    float* PU   = ws;  ws += (size_t)BB * (NN + 1) * FF;   // 4,196,352
    float* PW   = ws;  ws += (size_t)BB * (NN + 1) * FF;
    int* PERM = (int*)ws;  ws += BB * NN;
    int* KIDX = (int*)ws;  // ws += BB * NN;
    // total ~51.5 MB of workspace

    k_wh     <<<(BB * NN) / 32, 256, 0, stream>>>(h, W, a, Wh, f1, f2);
    k_sort   <<<BB, 1024, 0, stream>>>(f1, f2, Uarr, Warr, PERM, KIDX);
    k_chunk  <<<BB * 16, 128, 0, stream>>>(Wh, Uarr, Warr, PERM, CU, CW);
    k_offsets<<<BB, 128, 0, stream>>>(CU, CW);
    k_prefix <<<BB * 16, 128, 0, stream>>>(Wh, Uarr, Warr, PERM, CU, CW, PU, PW);
    k_out    <<<(BB * NN) / 2, 256, 0, stream>>>(PU, PW, f1, KIDX, out);
}

// Round 2
// 390.931 us; speedup vs baseline: 1.0440x; 1.0440x over previous
//
#include <hip/hip_runtime.h>

#define BB 16
#define NN 2048
#define FF 128
#define NEG 0.01f
#define CH 32          // chunks per batch for vector prefix sums
#define CL (NN / CH)   // chunk length = 64

// ---------------------------------------------------------------------------
// K1: Wh = h @ W  (fp32, LDS-tiled), fused f1 = Wh·a1, f2 = Wh·a2
// ---------------------------------------------------------------------------
__global__ __launch_bounds__(256) void k_wh(const float* __restrict__ h,
                                            const float* __restrict__ Wg,
                                            const float* __restrict__ a,
                                            float* __restrict__ Wh,
                                            float* __restrict__ f1,
                                            float* __restrict__ f2) {
    __shared__ float Ws[64 * 128];   // [k][f] half-K tile (32 KB)
    __shared__ float hsT[64 * 36];   // [k][row] transposed h tile, pad 36 (9 KB)

    const int tid  = threadIdx.x;
    const int fg   = tid & 31;        // f-group
    const int slot = tid >> 5;        // row-slot 0..7
    const int f4   = fg * 4;
    const int rowBase = blockIdx.x * 32;

    float acc[4][4];
#pragma unroll
    for (int r = 0; r < 4; ++r)
#pragma unroll
        for (int c = 0; c < 4; ++c) acc[r][c] = 0.f;

    const float4* Wg4 = (const float4*)Wg;
    const float4* hg4 = (const float4*)h;

    for (int kh = 0; kh < 128; kh += 64) {
        __syncthreads();
        for (int idx = tid; idx < 64 * 32; idx += 256) {
            int kk = idx >> 5, ff = idx & 31;
            ((float4*)Ws)[kk * 32 + ff] = Wg4[(size_t)(kh + kk) * 32 + ff];
        }
#pragma unroll
        for (int pass = 0; pass < 2; ++pass) {
            int idx = pass * 256 + tid;            // 0..511
            int kq = idx & 15, row = idx >> 4;     // kq 0..15, row 0..31
            float4 h4 = hg4[(size_t)(rowBase + row) * 32 + (kh >> 2) + kq];
            hsT[(kq * 4 + 0) * 36 + row] = h4.x;
            hsT[(kq * 4 + 1) * 36 + row] = h4.y;
            hsT[(kq * 4 + 2) * 36 + row] = h4.z;
            hsT[(kq * 4 + 3) * 36 + row] = h4.w;
        }
        __syncthreads();
#pragma unroll 8
        for (int kk = 0; kk < 64; ++kk) {
            float4 wv = *(const float4*)&Ws[kk * 128 + f4];
            float4 hv = *(const float4*)&hsT[kk * 36 + slot * 4];
            acc[0][0] += hv.x * wv.x; acc[0][1] += hv.x * wv.y; acc[0][2] += hv.x * wv.z; acc[0][3] += hv.x * wv.w;
            acc[1][0] += hv.y * wv.x; acc[1][1] += hv.y * wv.y; acc[1][2] += hv.y * wv.z; acc[1][3] += hv.y * wv.w;
            acc[2][0] += hv.z * wv.x; acc[2][1] += hv.z * wv.y; acc[2][2] += hv.z * wv.z; acc[2][3] += hv.z * wv.w;
            acc[3][0] += hv.w * wv.x; acc[3][1] += hv.w * wv.y; acc[3][2] += hv.w * wv.z; acc[3][3] += hv.w * wv.w;
        }
    }

    const float4* ag4 = (const float4*)a;
    float4 a1v = ag4[fg];
    float4 a2v = ag4[32 + fg];

#pragma unroll
    for (int r = 0; r < 4; ++r) {
        int row = rowBase + slot * 4 + r;
        float4 o; o.x = acc[r][0]; o.y = acc[r][1]; o.z = acc[r][2]; o.w = acc[r][3];
        *(float4*)&Wh[(size_t)row * 128 + f4] = o;
        float p1 = acc[r][0] * a1v.x + acc[r][1] * a1v.y + acc[r][2] * a1v.z + acc[r][3] * a1v.w;
        float p2 = acc[r][0] * a2v.x + acc[r][1] * a2v.y + acc[r][2] * a2v.z + acc[r][3] * a2v.w;
#pragma unroll
        for (int m = 16; m >= 1; m >>= 1) {
            p1 += __shfl_xor(p1, m);
            p2 += __shfl_xor(p2, m);
        }
        if (fg == 0) { f1[row] = p1; f2[row] = p2; }
    }
}

// ---------------------------------------------------------------------------
// wave-level inclusive scan (width 64)
// ---------------------------------------------------------------------------
__device__ __forceinline__ float wave_incl_scan(float s, int lane) {
#pragma unroll
    for (int m = 1; m <= 32; m <<= 1) {
        float o = __shfl_up(s, m);
        if (lane >= m) s += o;
    }
    return s;
}

#define WAVE_SYNC() do { __builtin_amdgcn_wave_barrier(); asm volatile("" ::: "memory"); } while (0)

// ---------------------------------------------------------------------------
// K2: 32 blocks x 1024 threads.
//  task 0 (blocks 0-15): sort f1 asc -> SF1g; shuffle scans -> PAg (exclusive
//    prefix of exp(0.01*sf1), length N+1) and SAg (suffix of exp(sf1), N+1).
//  task 1 (blocks 16-31): sort (f2,idx) pairs -> SKg, PERM; KIDX[i] =
//    #{t : sf2[t] <= -f1[i]} via LDS binary search.
// Bitonic phases with partner distance j<=64 are wave-local (each wave owns a
// 128-element window) -> no __syncthreads needed; barriers only for j>=128.
// ---------------------------------------------------------------------------
__global__ __launch_bounds__(1024) void k_sort2(const float* __restrict__ f1,
                                                const float* __restrict__ f2,
                                                float* __restrict__ SF1g,
                                                float* __restrict__ PAg,
                                                float* __restrict__ SAg,
                                                float* __restrict__ SKg,
                                                int* __restrict__ PERM,
                                                int* __restrict__ KIDX) {
    __shared__ float sKey[NN];
    __shared__ int   sIdx[NN];
    __shared__ float wtot[16];

    const int tid  = threadIdx.x;
    const int lane = tid & 63;
    const int w    = tid >> 6;
    const int b    = blockIdx.x & 15;
    const int task = blockIdx.x >> 4;

    const float* f1b = f1 + b * NN;
    const float* f2b = f2 + b * NN;

    if (task == 0) {
        for (int i = tid; i < NN; i += 1024) sKey[i] = f1b[i];
    } else {
        for (int i = tid; i < NN; i += 1024) { sKey[i] = f2b[i]; sIdx[i] = i; }
    }

    // ---- bitonic sort ascending; barrier only around cross-wave phases ----
    int prevj = 1024;  // force barrier before first phase (covers initial load)
    for (int k = 2; k <= NN; k <<= 1) {
        for (int j = k >> 1; j > 0; j >>= 1) {
            if (j >= 128 || prevj >= 128) __syncthreads();
            else WAVE_SYNC();
            int mask = j - 1;
            int i   = ((tid & ~mask) << 1) | (tid & mask);
            int ixj = i | j;
            bool up = ((i & k) == 0);
            float av = sKey[i], bv = sKey[ixj];
            if ((av > bv) == up) {
                sKey[i] = bv; sKey[ixj] = av;
                if (task == 1) { int t2 = sIdx[i]; sIdx[i] = sIdx[ixj]; sIdx[ixj] = t2; }
            }
            prevj = j;
        }
    }
    __syncthreads();

    if (task == 0) {
        for (int i = tid; i < NN; i += 1024) SF1g[b * NN + i] = sKey[i];
        const size_t pbase = (size_t)b * (NN + 1);
        // ---- scan 1: exclusive prefix of exp(0.01 * sf1) ----
        {
            float a0 = expf(NEG * sKey[2 * tid]);
            float a1 = expf(NEG * sKey[2 * tid + 1]);
            float s = a0 + a1;
            float v = wave_incl_scan(s, lane);
            if (lane == 63) wtot[w] = v;
            __syncthreads();
            float off = 0.f;
#pragma unroll
            for (int ww = 0; ww < 16; ++ww) off += (ww < w) ? wtot[ww] : 0.f;
            float excl = off + v - s;
            PAg[pbase + 2 * tid]     = excl;
            PAg[pbase + 2 * tid + 1] = excl + a0;
            if (tid == 1023) PAg[pbase + NN] = off + v;
        }
        __syncthreads();   // protect wtot reuse
        // ---- scan 2: suffix sums of exp(sf1) (scan reversed array) ----
        {
            float y0 = expf(sKey[NN - 1 - 2 * tid]);
            float y1 = expf(sKey[NN - 2 - 2 * tid]);
            float s = y0 + y1;
            float v = wave_incl_scan(s, lane);
            if (lane == 63) wtot[w] = v;
            __syncthreads();
            float off = 0.f;
#pragma unroll
            for (int ww = 0; ww < 16; ++ww) off += (ww < w) ? wtot[ww] : 0.f;
            SAg[pbase + NN - 1 - 2 * tid] = off + (v - s) + y0;
            SAg[pbase + NN - 2 - 2 * tid] = off + v;
            if (tid == 0) SAg[pbase + NN] = 0.f;
        }
    } else {
        for (int i = tid; i < NN; i += 1024) {
            SKg[b * NN + i]  = sKey[i];
            PERM[b * NN + i] = sIdx[i];
        }
        for (int i = tid; i < NN; i += 1024) {
            float tau = -f1b[i];
            int lo = 0, hi = NN;
            while (lo < hi) { int m = (lo + hi) >> 1; if (sKey[m] <= tau) lo = m + 1; else hi = m; }
            KIDX[b * NN + i] = lo;
        }
    }
}

// ---------------------------------------------------------------------------
// K3: per-j softmax denominators -> u_j = e^{f2}/D, w_j = e^{0.01 f2}/D
// ---------------------------------------------------------------------------
__global__ __launch_bounds__(256) void k_uw(const float* __restrict__ SF1g,
                                            const float* __restrict__ PAg,
                                            const float* __restrict__ SAg,
                                            const float* __restrict__ SKg,
                                            float* __restrict__ Uarr,
                                            float* __restrict__ Warr) {
    __shared__ float sS[NN];
    __shared__ float sP[NN + 1];
    __shared__ float sA[NN + 1];
    const int b = blockIdx.x, tid = threadIdx.x;
    const size_t pbase = (size_t)b * (NN + 1);
    for (int i = tid; i < NN; i += 256) sS[i] = SF1g[b * NN + i];
    for (int i = tid; i < NN + 1; i += 256) { sP[i] = PAg[pbase + i]; sA[i] = SAg[pbase + i]; }
    __syncthreads();
    for (int t = tid; t < NN; t += 256) {
        float f2v = SKg[b * NN + t];
        float tau = -f2v;
        int lo = 0, hi = NN;
        while (lo < hi) { int m = (lo + hi) >> 1; if (sS[m] <= tau) lo = m + 1; else hi = m; }
        float eS = expf(NEG * f2v);
        float eF = expf(f2v);
        float inv = 1.0f / (eS * sP[lo] + eF * sA[lo]);
        Uarr[b * NN + t] = eF * inv;
        Warr[b * NN + t] = eS * inv;
    }
}

// ---------------------------------------------------------------------------
// K4: chunk totals for the 128-wide vector prefix sums (CH chunks x CL t)
// ---------------------------------------------------------------------------
__global__ __launch_bounds__(128) void k_chunk(const float* __restrict__ Wh,
                                               const float* __restrict__ Uarr,
                                               const float* __restrict__ Warr,
                                               const int* __restrict__ PERM,
                                               float* __restrict__ CU,
                                               float* __restrict__ CW) {
    int blk = blockIdx.x;               // b*CH + c
    int b = blk / CH, c = blk % CH;
    int f = threadIdx.x;
    int base = b * NN + c * CL;
    const float* Whb = Wh + (size_t)b * NN * FF;
    float aU = 0.f, aW = 0.f;
#pragma unroll 4
    for (int t = 0; t < CL; ++t) {
        int j = PERM[base + t];
        float uv = Uarr[base + t], wv = Warr[base + t];
        float whv = Whb[(size_t)j * FF + f];
        aU += uv * whv; aW += wv * whv;
    }
    CU[(size_t)blk * 128 + f] = aU;
    CW[(size_t)blk * 128 + f] = aW;
}

// ---------------------------------------------------------------------------
// K5: in-place exclusive scan of the CH chunk totals per (b,f)
// ---------------------------------------------------------------------------
__global__ __launch_bounds__(128) void k_offsets(float* __restrict__ CU,
                                                 float* __restrict__ CW) {
    int b = blockIdx.x, f = threadIdx.x;
    float aU = 0.f, aW = 0.f;
#pragma unroll
    for (int c = 0; c < CH; ++c) {
        size_t idx = (size_t)(b * CH + c) * 128 + f;
        float tU = CU[idx], tW = CW[idx];
        CU[idx] = aU; CW[idx] = aW;
        aU += tU; aW += tW;
    }
}

// ---------------------------------------------------------------------------
// K6: write exclusive vector prefix sums PU/PW (rows 0..N; row N = totals)
// ---------------------------------------------------------------------------
__global__ __launch_bounds__(128) void k_prefix(const float* __restrict__ Wh,
                                                const float* __restrict__ Uarr,
                                                const float* __restrict__ Warr,
                                                const int* __restrict__ PERM,
                                                const float* __restrict__ CU,
                                                const float* __restrict__ CW,
                                                float* __restrict__ PU,
                                                float* __restrict__ PW) {
    int blk = blockIdx.x;
    int b = blk / CH, c = blk % CH;
    int f = threadIdx.x;
    int base = b * NN + c * CL;
    const float* Whb = Wh + (size_t)b * NN * FF;
    float aU = CU[(size_t)blk * 128 + f];
    float aW = CW[(size_t)blk * 128 + f];
    size_t rowB = (size_t)b * (NN + 1);
#pragma unroll 4
    for (int t = 0; t < CL; ++t) {
        int g = c * CL + t;
        PU[(rowB + g) * FF + f] = aU;
        PW[(rowB + g) * FF + f] = aW;
        int j = PERM[base + t];
        float whv = Whb[(size_t)j * FF + f];
        aU += Uarr[base + t] * whv;
        aW += Warr[base + t] * whv;
    }
    if (c == CH - 1) {
        PU[(rowB + NN) * FF + f] = aU;
        PW[(rowB + NN) * FF + f] = aW;
    }
}

// ---------------------------------------------------------------------------
// K7: out[b,i,f] = e^{0.01 f1i} * PW[k_i] + e^{f1i} * (TotU - PU[k_i])
// ---------------------------------------------------------------------------
__global__ __launch_bounds__(256) void k_out(const float* __restrict__ PU,
                                             const float* __restrict__ PW,
                                             const float* __restrict__ f1,
                                             const int* __restrict__ KIDX,
                                             float* __restrict__ out) {
    int rowId = blockIdx.x * 2 + (threadIdx.x >> 7);
    int f = threadIdx.x & 127;
    int b = rowId >> 11;
    int k = KIDX[rowId];
    float f1v = f1[rowId];
    float alpha = expf(NEG * f1v);
    float beta  = expf(f1v);
    size_t rowB = (size_t)b * (NN + 1);
    float totU = PU[(rowB + NN) * FF + f];
    float pu   = PU[(rowB + k) * FF + f];
    float pw   = PW[(rowB + k) * FF + f];
    out[(size_t)rowId * FF + f] = alpha * pw + beta * (totU - pu);
}

// ---------------------------------------------------------------------------
extern "C" void kernel_launch(void* const* d_in, const int* in_sizes, int n_in,
                              void* d_out, int out_size, void* d_ws, size_t ws_size,
                              hipStream_t stream) {
    const float* h  = (const float*)d_in[0];
    // d_in[1] = adj — unused by the reference; never read.
    const float* W  = (const float*)d_in[2];
    const float* a  = (const float*)d_in[3];
    float* out = (float*)d_out;

    float* ws = (float*)d_ws;
    float* Wh   = ws;  ws += (size_t)BB * NN * FF;         // 4,194,304
    float* f1   = ws;  ws += BB * NN;
    float* f2   = ws;  ws += BB * NN;
    float* SF1  = ws;  ws += BB * NN;
    float* PA   = ws;  ws += BB * (NN + 1);                // 32,784
    float* SA   = ws;  ws += BB * (NN + 1);
    float* SK   = ws;  ws += BB * NN;
    float* Uarr = ws;  ws += BB * NN;
    float* Warr = ws;  ws += BB * NN;
    float* CU   = ws;  ws += BB * CH * FF;                 // 65,536
    float* CW   = ws;  ws += BB * CH * FF;
    float* PU   = ws;  ws += (size_t)BB * (NN + 1) * FF;   // 4,196,352
    float* PW   = ws;  ws += (size_t)BB * (NN + 1) * FF;
    int* PERM = (int*)ws;  ws += BB * NN;
    int* KIDX = (int*)ws;  // ~52 MB total

    k_wh     <<<(BB * NN) / 32, 256, 0, stream>>>(h, W, a, Wh, f1, f2);
    k_sort2  <<<2 * BB, 1024, 0, stream>>>(f1, f2, SF1, PA, SA, SK, PERM, KIDX);
    k_uw     <<<BB, 256, 0, stream>>>(SF1, PA, SA, SK, Uarr, Warr);
    k_chunk  <<<BB * CH, 128, 0, stream>>>(Wh, Uarr, Warr, PERM, CU, CW);
    k_offsets<<<BB, 128, 0, stream>>>(CU, CW);
    k_prefix <<<BB * CH, 128, 0, stream>>>(Wh, Uarr, Warr, PERM, CU, CW, PU, PW);
    k_out    <<<(BB * NN) / 2, 256, 0, stream>>>(PU, PW, f1, KIDX, out);
}